// Round 2
// baseline (513.861 us; speedup 1.0000x reference)
//
#include <hip/hip_runtime.h>
#include <math.h>

#define VOCAB 32000
#define NB 16        // batch
#define NH 12        // heads
#define DEC_T 128
#define ALEN 512
#define DD 768
#define NT 512       // threads per block
#define NW 8         // waves per block
#define V4 8000      // VOCAB/4 float4 per row
#define CHUNKS 16    // NT*CHUNKS = 8192 >= V4
#define HSZ 1024     // hash slots (load factor <= 0.5)
#define BMW 1000     // bitmap words (32000/32)

typedef float f4 __attribute__((ext_vector_type(4)));

__device__ inline float wave_sum(float v) {
#pragma unroll
  for (int o = 32; o > 0; o >>= 1) v += __shfl_down(v, o, 64);
  return v;
}
__device__ inline float wave_max(float v) {
#pragma unroll
  for (int o = 32; o > 0; o >>= 1) v = fmaxf(v, __shfl_down(v, o, 64));
  return v;
}

// block=512: LDS ~13KB + launch_bounds(512,4) -> 2 blocks/CU co-resident
// (16 waves/CU), VGPR cap 128. The asm "+v" pin below forces the 16xfloat4
// row cache to stay register-resident (round-1 compiler re-loaded fo 3x).
__global__ __launch_bounds__(NT, 4) void pg_kernel(
    const float* __restrict__ dec, const float* __restrict__ fo,
    const float* __restrict__ attnw, const int* __restrict__ ids,
    const float* __restrict__ Wpg, const float* __restrict__ bpg,
    float* __restrict__ out) {
  __shared__ int      h_key[HSZ];   // scatter hash: vocab id -> combined mass
  __shared__ float    h_val[HSZ];
  __shared__ unsigned bm[BMW];      // per-vocab "scattered" bitmap
  __shared__ float    s_red[NW];
  __shared__ float    s_res[8];

  const int bt = blockIdx.x;        // b*DEC_T + t
  const int b = bt / DEC_T;
  const int t = bt - b * DEC_T;
  const int tid = threadIdx.x;
  const int lane = tid & 63;
  const int wid = tid >> 6;

  // ---- issue row loads early; stays in flight during pgen/attn phases ----
  const f4* row4 = (const f4*)(fo + (size_t)bt * VOCAB);
  f4 r[CHUNKS];
#pragma unroll
  for (int c = 0; c < CHUNKS; ++c) {
    int idx = c * NT + tid;
    if (idx < V4) {
      r[c] = row4[idx];
    } else {
      f4 z = {0.f, 0.f, 0.f, 0.f};
      r[c] = z;
    }
  }
#pragma unroll
  for (int c = 0; c < CHUNKS; ++c) asm volatile("" : "+v"(r[c]));  // pin

  // ---- init hash + bitmap ----
  for (int i = tid; i < HSZ; i += NT) { h_key[i] = -1; h_val[i] = 0.f; }
  for (int i = tid; i < BMW; i += NT) bm[i] = 0u;

  // ---- p_gen = sigmoid(dec[bt,:] . Wpg + b) ----
  const float* drow = dec + (size_t)bt * DD;
  float pp = drow[tid] * Wpg[tid];
  if (tid < DD - NT) pp += drow[tid + NT] * Wpg[tid + NT];
  pp = wave_sum(pp);
  if (lane == 0) s_red[wid] = pp;
  __syncthreads();   // also covers hash/bitmap init completion
  if (tid == 0) {
    float acc = 0.f;
    for (int i = 0; i < NW; ++i) acc += s_red[i];
    s_res[0] = acc;
  }
  __syncthreads();
  const float pgen = 1.f / (1.f + __expf(-(s_res[0] + bpg[0])));

  // ---- attention: mean over heads, softmax over ALEN (ALEN==NT) ----
  const float* ap = attnw + ((size_t)b * NH * DEC_T + t) * ALEN + tid;
  float s = 0.f;
#pragma unroll
  for (int h = 0; h < NH; ++h) s += ap[(size_t)h * DEC_T * ALEN];
  const float amean = s * (1.f / NH);
  float am = wave_max(amean);
  if (lane == 0) s_red[wid] = am;
  __syncthreads();
  if (tid == 0) {
    float acc = -INFINITY;
    for (int i = 0; i < NW; ++i) acc = fmaxf(acc, s_red[i]);
    s_res[1] = acc;
  }
  __syncthreads();
  const float ae = __expf(amean - s_res[1]);
  float as = wave_sum(ae);
  if (lane == 0) s_red[wid] = as;
  __syncthreads();
  if (tid == 0) {
    float acc = 0.f;
    for (int i = 0; i < NW; ++i) acc += s_red[i];
    s_res[2] = acc;
  }
  __syncthreads();
  const float ainv = (1.f - pgen) / s_res[2];

  // ---- scatter: bitmap + hash insert (duplicates combined by atomicAdd) ----
  {
    const int id = ids[b * ALEN + tid];
    const float contrib = ae * ainv;
    atomicOr(&bm[id >> 5], 1u << (id & 31));
    unsigned h = ((unsigned)id * 2654435761u) >> 22;
    while (true) {
      int old = atomicCAS(&h_key[h], -1, id);
      if (old == -1 || old == id) { atomicAdd(&h_val[h], contrib); break; }
      h = (h + 1) & (HSZ - 1);
    }
  }

  // ---- vocab softmax: max (from pinned registers) ----
  float m = -INFINITY;
#pragma unroll
  for (int c = 0; c < CHUNKS; ++c) {
    int idx = c * NT + tid;
    if (idx < V4)
      m = fmaxf(m, fmaxf(fmaxf(r[c].x, r[c].y), fmaxf(r[c].z, r[c].w)));
  }
  m = wave_max(m);
  if (lane == 0) s_red[wid] = m;
  __syncthreads();   // also the insert-completion barrier
  if (tid == 0) {
    float acc = -INFINITY;
    for (int i = 0; i < NW; ++i) acc = fmaxf(acc, s_red[i]);
    s_res[3] = acc;
  }
  __syncthreads();
  const float fm = s_res[3];

  // ---- vocab softmax: denominator ----
  float zs = 0.f;
#pragma unroll
  for (int c = 0; c < CHUNKS; ++c) {
    int idx = c * NT + tid;
    if (idx < V4)
      zs += __expf(r[c].x - fm) + __expf(r[c].y - fm) +
            __expf(r[c].z - fm) + __expf(r[c].w - fm);
  }
  zs = wave_sum(zs);
  if (lane == 0) s_red[wid] = zs;
  __syncthreads();
  if (tid == 0) {
    float acc = 0.f;
    for (int i = 0; i < NW; ++i) acc += s_red[i];
    s_res[4] = acc;
  }
  __syncthreads();
  const float P = pgen / s_res[4];       // pgen * invZ
  const float C = __logf(P) - fm;        // fast-path constant

  // ---- output: out = x + C, except scattered slots (bitmap-flagged) ----
#define FIXUP(comp, k)                                                     \
  if (bits & (1u << (k))) {                                                \
    int v = idx * 4 + (k);                                                 \
    unsigned h = ((unsigned)v * 2654435761u) >> 22;                        \
    while (h_key[h] != v) h = (h + 1) & (HSZ - 1);                         \
    o.comp = __logf(P * __expf(x.comp - fm) + h_val[h]);                   \
  }

  f4* out4 = (f4*)(out + (size_t)bt * VOCAB);
#pragma unroll
  for (int c = 0; c < CHUNKS; ++c) {
    int idx = c * NT + tid;
    if (idx < V4) {
      const f4 x = r[c];
      f4 o = x + C;
      // elements 4*idx..4*idx+3 share bitmap word idx>>3
      unsigned bits = (bm[idx >> 3] >> ((idx & 7) * 4)) & 0xFu;
      if (bits) {
        FIXUP(x, 0)
        FIXUP(y, 1)
        FIXUP(z, 2)
        FIXUP(w, 3)
      }
      out4[idx] = o;
    }
  }
#undef FIXUP
}

extern "C" void kernel_launch(void* const* d_in, const int* in_sizes, int n_in,
                              void* d_out, int out_size, void* d_ws, size_t ws_size,
                              hipStream_t stream) {
  (void)in_sizes; (void)n_in; (void)out_size; (void)d_ws; (void)ws_size;
  const float* dec   = (const float*)d_in[0];   // (16,128,768)
  const float* fo    = (const float*)d_in[1];   // (16,128,32000)
  const float* attnw = (const float*)d_in[2];   // (16,12,128,512)
  const int*   ids   = (const int*)  d_in[3];   // (16,512)
  const float* Wpg   = (const float*)d_in[4];   // (768,1)
  const float* bpg   = (const float*)d_in[5];   // (1,)
  float* out = (float*)d_out;                   // (16,128,32000)

  pg_kernel<<<NB * DEC_T, NT, 0, stream>>>(dec, fo, attnw, ids, Wpg, bpg, out);
}